// Round 1
// baseline (396.055 us; speedup 1.0000x reference)
//
#include <hip/hip_runtime.h>

#define S 128
#define SS (S*S)
#define B 8
#define NEG_INF (-3.402823466e+38f)

// ws layout (floats/uints):
// maps[vol(2)][t(3)][b(8)][SS] : t=0 Pa(float, [i][j]), t=1 Pb(mapped uint, [j][k]), t=2 Pc(mapped uint, [i][k])
#define MAPS_ELEMS (2*3*B*SS)        // 786432
#define LOSSACC_OFF MAPS_ELEMS       // 5 floats (+3 pad)
#define DICEACC_OFF (MAPS_ELEMS + 8) // 24 floats: [b][{at,aa,tt}]
#define WS_TOTAL_ELEMS (MAPS_ELEMS + 8 + 24)

__device__ __forceinline__ unsigned mapf(float f) {
  unsigned u = __float_as_uint(f);
  return (u & 0x80000000u) ? ~u : (u | 0x80000000u);
}
__device__ __forceinline__ float unmapf(unsigned u) {
  return (u & 0x80000000u) ? __uint_as_float(u & 0x7FFFFFFFu) : __uint_as_float(~u);
}
__device__ __forceinline__ float4 max4(float4 a, float4 b) {
  return make_float4(fmaxf(a.x,b.x), fmaxf(a.y,b.y), fmaxf(a.z,b.z), fmaxf(a.w,b.w));
}

// Phase 1: stream channel-1 of both volumes once; projections + dice sums.
__global__ __launch_bounds__(256) void proj_dice_kernel(
    const float* __restrict__ gin, const float* __restrict__ gtg,
    float* __restrict__ ws)
{
  const int jc  = blockIdx.x;   // 0..3  -> j chunk of 32
  const int ic  = blockIdx.y;   // 0..7  -> i chunk of 16
  const int b   = blockIdx.z;   // 0..7
  const int tid = threadIdx.x;
  const int rowg = tid >> 5;    // 0..7
  const int lane = tid & 31;
  const int k0 = lane << 2;
  const int i0 = ic << 4;
  const int j0 = jc << 5;

  const float* __restrict__ xin = gin + (size_t)(2*b + 1) * (size_t)(S*SS);
  const float* __restrict__ xtg = gtg + (size_t)(2*b + 1) * (size_t)(S*SS);

  float*    paI = ws + (size_t)(0*B + b) * SS;
  float*    paT = ws + (size_t)(3*B + b) * SS;
  unsigned* pbI = (unsigned*)ws + (size_t)(1*B + b) * SS;
  unsigned* pbT = (unsigned*)ws + (size_t)(4*B + b) * SS;
  unsigned* pcI = (unsigned*)ws + (size_t)(2*B + b) * SS;
  unsigned* pcT = (unsigned*)ws + (size_t)(5*B + b) * SS;

  __shared__ float lcm[2][8][S];
  __shared__ float lred[3][4];

  float4 pbi[4], pbt[4];
  #pragma unroll
  for (int s = 0; s < 4; ++s) {
    pbi[s] = make_float4(NEG_INF, NEG_INF, NEG_INF, NEG_INF);
    pbt[s] = pbi[s];
  }
  float s_at = 0.f, s_aa = 0.f, s_tt = 0.f;

  for (int ib = 0; ib < 16; ++ib) {
    const int i = i0 + ib;
    float4 cmi = make_float4(NEG_INF, NEG_INF, NEG_INF, NEG_INF);
    float4 cmt = cmi;
    #pragma unroll
    for (int s = 0; s < 4; ++s) {
      const int j = j0 + s*8 + rowg;
      const size_t off = (size_t)i*SS + (size_t)j*S + k0;
      const float4 a = *(const float4*)(xin + off);
      const float4 t = *(const float4*)(xtg + off);
      s_at = fmaf(a.x,t.x, fmaf(a.y,t.y, fmaf(a.z,t.z, fmaf(a.w,t.w, s_at))));
      s_aa = fmaf(a.x,a.x, fmaf(a.y,a.y, fmaf(a.z,a.z, fmaf(a.w,a.w, s_aa))));
      s_tt = fmaf(t.x,t.x, fmaf(t.y,t.y, fmaf(t.z,t.z, fmaf(t.w,t.w, s_tt))));
      // row max over k -> Pa[i][j]
      float rmi = fmaxf(fmaxf(a.x,a.y), fmaxf(a.z,a.w));
      float rmt = fmaxf(fmaxf(t.x,t.y), fmaxf(t.z,t.w));
      #pragma unroll
      for (int m = 16; m >= 1; m >>= 1) {
        rmi = fmaxf(rmi, __shfl_xor(rmi, m, 64));
        rmt = fmaxf(rmt, __shfl_xor(rmt, m, 64));
      }
      if (lane == 0) {
        paI[i*S + j] = rmi;
        paT[i*S + j] = rmt;
      }
      cmi = max4(cmi, a);
      cmt = max4(cmt, t);
      pbi[s] = max4(pbi[s], a);
      pbt[s] = max4(pbt[s], t);
    }
    // flush column max (over j) for this i -> Pc[i][k]
    __syncthreads();
    lcm[0][rowg][k0+0] = cmi.x; lcm[0][rowg][k0+1] = cmi.y;
    lcm[0][rowg][k0+2] = cmi.z; lcm[0][rowg][k0+3] = cmi.w;
    lcm[1][rowg][k0+0] = cmt.x; lcm[1][rowg][k0+1] = cmt.y;
    lcm[1][rowg][k0+2] = cmt.z; lcm[1][rowg][k0+3] = cmt.w;
    __syncthreads();
    {
      const int vol = tid >> 7;
      const int k   = tid & 127;
      float m = lcm[vol][0][k];
      #pragma unroll
      for (int r = 1; r < 8; ++r) m = fmaxf(m, lcm[vol][r][k]);
      unsigned* dst = vol ? pcT : pcI;
      atomicMax(dst + i*S + k, mapf(m));
    }
  }

  // flush Pb[j][k] (max over this block's 16 i's)
  #pragma unroll
  for (int s = 0; s < 4; ++s) {
    const int j = j0 + s*8 + rowg;
    atomicMax(pbI + j*S + k0+0, mapf(pbi[s].x));
    atomicMax(pbI + j*S + k0+1, mapf(pbi[s].y));
    atomicMax(pbI + j*S + k0+2, mapf(pbi[s].z));
    atomicMax(pbI + j*S + k0+3, mapf(pbi[s].w));
    atomicMax(pbT + j*S + k0+0, mapf(pbt[s].x));
    atomicMax(pbT + j*S + k0+1, mapf(pbt[s].y));
    atomicMax(pbT + j*S + k0+2, mapf(pbt[s].z));
    atomicMax(pbT + j*S + k0+3, mapf(pbt[s].w));
  }

  // dice reduction
  float v0 = s_at, v1 = s_aa, v2 = s_tt;
  #pragma unroll
  for (int m = 32; m >= 1; m >>= 1) {
    v0 += __shfl_xor(v0, m, 64);
    v1 += __shfl_xor(v1, m, 64);
    v2 += __shfl_xor(v2, m, 64);
  }
  const int wid = tid >> 6;
  if ((tid & 63) == 0) { lred[0][wid] = v0; lred[1][wid] = v1; lred[2][wid] = v2; }
  __syncthreads();
  if (tid == 0) {
    float a0 = lred[0][0] + lred[0][1] + lred[0][2] + lred[0][3];
    float a1 = lred[1][0] + lred[1][1] + lred[1][2] + lred[1][3];
    float a2 = lred[2][0] + lred[2][1] + lred[2][2] + lred[2][3];
    atomicAdd(ws + DICEACC_OFF + b*3 + 0, a0);
    atomicAdd(ws + DICEACC_OFF + b*3 + 1, a1);
    atomicAdd(ws + DICEACC_OFF + b*3 + 2, a2);
  }
}

// Phase 2: maxpool at 5 scales, sum over 3 projections, |G - P|, accumulate.
__global__ __launch_bounds__(256) void pool_loss_kernel(float* __restrict__ ws)
{
  const int lvl = blockIdx.x;   // 0..4 -> k = 2,4,8,16,32
  const int b   = blockIdx.y;
  const int k = 2 << lvl;
  const int n = S / k;
  const float* mf = ws;
  const unsigned* mu = (const unsigned*)ws;
  const int tid = threadIdx.x;
  float part = 0.f;
  for (int cell = tid; cell < n*n; cell += 256) {
    const int u = cell / n;
    const int v = cell % n;
    float sp = 0.f, sg = 0.f;
    #pragma unroll
    for (int t = 0; t < 3; ++t) {
      const size_t basP = ((size_t)(0*3 + t)*B + b) * SS;
      const size_t basG = ((size_t)(1*3 + t)*B + b) * SS;
      float mp = NEG_INF, mg = NEG_INF;
      for (int r = 0; r < k; ++r) {
        const size_t ro = (size_t)(u*k + r)*S + (size_t)(v*k);
        for (int c = 0; c < k; ++c) {
          float fp, fg;
          if (t == 0) { fp = mf[basP + ro + c];        fg = mf[basG + ro + c]; }
          else        { fp = unmapf(mu[basP + ro + c]); fg = unmapf(mu[basG + ro + c]); }
          mp = fmaxf(mp, fp);
          mg = fmaxf(mg, fg);
        }
      }
      sp += mp; sg += mg;
    }
    part += fabsf(sg - sp);
  }
  #pragma unroll
  for (int m = 32; m >= 1; m >>= 1) part += __shfl_xor(part, m, 64);
  __shared__ float red[4];
  const int wid = tid >> 6;
  if ((tid & 63) == 0) red[wid] = part;
  __syncthreads();
  if (tid == 0) atomicAdd(ws + LOSSACC_OFF + lvl, red[0] + red[1] + red[2] + red[3]);
}

// Phase 3: combine.
__global__ void finalize_kernel(const float* __restrict__ ws, float* __restrict__ out)
{
  if (threadIdx.x == 0) {
    float topo = 0.f;
    #pragma unroll
    for (int l = 0; l < 5; ++l) {
      const int k = 2 << l;
      const int n = S / k;
      topo += ws[LOSSACC_OFF + l] / (float)(B * n * n);
    }
    topo *= 0.2f;
    float dsum = 0.f;
    for (int b = 0; b < B; ++b) {
      const float at = ws[DICEACC_OFF + b*3 + 0];
      const float aa = ws[DICEACC_OFF + b*3 + 1];
      const float tt = ws[DICEACC_OFF + b*3 + 2];
      dsum += (2.f*at + 1e-6f) / (aa + tt);
    }
    out[0] = topo + (1.f - dsum / (float)B);
  }
}

extern "C" void kernel_launch(void* const* d_in, const int* in_sizes, int n_in,
                              void* d_out, int out_size, void* d_ws, size_t ws_size,
                              hipStream_t stream)
{
  const float* gin = (const float*)d_in[0];
  const float* gtg = (const float*)d_in[1];
  float* ws  = (float*)d_ws;
  float* out = (float*)d_out;

  hipMemsetAsync(d_ws, 0, (size_t)WS_TOTAL_ELEMS * sizeof(float), stream);

  dim3 g1(4, 8, B), blk(256);
  proj_dice_kernel<<<g1, blk, 0, stream>>>(gin, gtg, ws);

  dim3 g2(5, B);
  pool_loss_kernel<<<g2, blk, 0, stream>>>(ws);

  finalize_kernel<<<1, 64, 0, stream>>>(ws, out);
}

// Round 2
// 101.336 us; speedup vs baseline: 3.9083x; 3.9083x over previous
//
#include <hip/hip_runtime.h>

#define S 128
#define SS (S*S)
#define B 8
#define NEG_INF (-3.402823466e+38f)

// ws layout (floats/uints):
// maps[vol(2)][t(3)][b(8)][SS] : t=0 Pa(float, [i][j]), t=1 Pb(mapped uint, [j][k]), t=2 Pc(mapped uint, [i][k])
#define MAPS_ELEMS (2*3*B*SS)        // 786432
#define LOSSACC_OFF MAPS_ELEMS       // 1 float topo accumulator (+7 pad)
#define DICEACC_OFF (MAPS_ELEMS + 8) // 24 floats: [b][{at,aa,tt}]
#define WS_TOTAL_ELEMS (MAPS_ELEMS + 8 + 24)

__device__ __forceinline__ unsigned mapf(float f) {
  unsigned u = __float_as_uint(f);
  return (u & 0x80000000u) ? ~u : (u | 0x80000000u);
}
__device__ __forceinline__ float unmapf(unsigned u) {
  return (u & 0x80000000u) ? __uint_as_float(u & 0x7FFFFFFFu) : __uint_as_float(~u);
}
__device__ __forceinline__ float4 max4(float4 a, float4 b) {
  return make_float4(fmaxf(a.x,b.x), fmaxf(a.y,b.y), fmaxf(a.z,b.z), fmaxf(a.w,b.w));
}

// Phase 1: stream channel-1 of both volumes once; projections + dice sums.
__global__ __launch_bounds__(256) void proj_dice_kernel(
    const float* __restrict__ gin, const float* __restrict__ gtg,
    float* __restrict__ ws)
{
  const int jc  = blockIdx.x;   // 0..3  -> j chunk of 32
  const int ic  = blockIdx.y;   // 0..7  -> i chunk of 16
  const int b   = blockIdx.z;   // 0..7
  const int tid = threadIdx.x;
  const int rowg = tid >> 5;    // 0..7
  const int lane = tid & 31;
  const int k0 = lane << 2;
  const int i0 = ic << 4;
  const int j0 = jc << 5;

  const float* __restrict__ xin = gin + (size_t)(2*b + 1) * (size_t)(S*SS);
  const float* __restrict__ xtg = gtg + (size_t)(2*b + 1) * (size_t)(S*SS);

  float*    paI = ws + (size_t)(0*B + b) * SS;
  float*    paT = ws + (size_t)(3*B + b) * SS;
  unsigned* pbI = (unsigned*)ws + (size_t)(1*B + b) * SS;
  unsigned* pbT = (unsigned*)ws + (size_t)(4*B + b) * SS;
  unsigned* pcI = (unsigned*)ws + (size_t)(2*B + b) * SS;
  unsigned* pcT = (unsigned*)ws + (size_t)(5*B + b) * SS;

  __shared__ float lcm[2][8][S];
  __shared__ float lred[3][4];

  float4 pbi[4], pbt[4];
  #pragma unroll
  for (int s = 0; s < 4; ++s) {
    pbi[s] = make_float4(NEG_INF, NEG_INF, NEG_INF, NEG_INF);
    pbt[s] = pbi[s];
  }
  float s_at = 0.f, s_aa = 0.f, s_tt = 0.f;

  for (int ib = 0; ib < 16; ++ib) {
    const int i = i0 + ib;
    float4 cmi = make_float4(NEG_INF, NEG_INF, NEG_INF, NEG_INF);
    float4 cmt = cmi;
    #pragma unroll
    for (int s = 0; s < 4; ++s) {
      const int j = j0 + s*8 + rowg;
      const size_t off = (size_t)i*SS + (size_t)j*S + k0;
      const float4 a = *(const float4*)(xin + off);
      const float4 t = *(const float4*)(xtg + off);
      s_at = fmaf(a.x,t.x, fmaf(a.y,t.y, fmaf(a.z,t.z, fmaf(a.w,t.w, s_at))));
      s_aa = fmaf(a.x,a.x, fmaf(a.y,a.y, fmaf(a.z,a.z, fmaf(a.w,a.w, s_aa))));
      s_tt = fmaf(t.x,t.x, fmaf(t.y,t.y, fmaf(t.z,t.z, fmaf(t.w,t.w, s_tt))));
      // row max over k -> Pa[i][j]
      float rmi = fmaxf(fmaxf(a.x,a.y), fmaxf(a.z,a.w));
      float rmt = fmaxf(fmaxf(t.x,t.y), fmaxf(t.z,t.w));
      #pragma unroll
      for (int m = 16; m >= 1; m >>= 1) {
        rmi = fmaxf(rmi, __shfl_xor(rmi, m, 64));
        rmt = fmaxf(rmt, __shfl_xor(rmt, m, 64));
      }
      if (lane == 0) {
        paI[i*S + j] = rmi;
        paT[i*S + j] = rmt;
      }
      cmi = max4(cmi, a);
      cmt = max4(cmt, t);
      pbi[s] = max4(pbi[s], a);
      pbt[s] = max4(pbt[s], t);
    }
    // flush column max (over j) for this i -> Pc[i][k]
    __syncthreads();
    lcm[0][rowg][k0+0] = cmi.x; lcm[0][rowg][k0+1] = cmi.y;
    lcm[0][rowg][k0+2] = cmi.z; lcm[0][rowg][k0+3] = cmi.w;
    lcm[1][rowg][k0+0] = cmt.x; lcm[1][rowg][k0+1] = cmt.y;
    lcm[1][rowg][k0+2] = cmt.z; lcm[1][rowg][k0+3] = cmt.w;
    __syncthreads();
    {
      const int vol = tid >> 7;
      const int k   = tid & 127;
      float m = lcm[vol][0][k];
      #pragma unroll
      for (int r = 1; r < 8; ++r) m = fmaxf(m, lcm[vol][r][k]);
      unsigned* dst = vol ? pcT : pcI;
      atomicMax(dst + i*S + k, mapf(m));
    }
  }

  // flush Pb[j][k] (max over this block's 16 i's)
  #pragma unroll
  for (int s = 0; s < 4; ++s) {
    const int j = j0 + s*8 + rowg;
    atomicMax(pbI + j*S + k0+0, mapf(pbi[s].x));
    atomicMax(pbI + j*S + k0+1, mapf(pbi[s].y));
    atomicMax(pbI + j*S + k0+2, mapf(pbi[s].z));
    atomicMax(pbI + j*S + k0+3, mapf(pbi[s].w));
    atomicMax(pbT + j*S + k0+0, mapf(pbt[s].x));
    atomicMax(pbT + j*S + k0+1, mapf(pbt[s].y));
    atomicMax(pbT + j*S + k0+2, mapf(pbt[s].z));
    atomicMax(pbT + j*S + k0+3, mapf(pbt[s].w));
  }

  // dice reduction
  float v0 = s_at, v1 = s_aa, v2 = s_tt;
  #pragma unroll
  for (int m = 32; m >= 1; m >>= 1) {
    v0 += __shfl_xor(v0, m, 64);
    v1 += __shfl_xor(v1, m, 64);
    v2 += __shfl_xor(v2, m, 64);
  }
  const int wid = tid >> 6;
  if ((tid & 63) == 0) { lred[0][wid] = v0; lred[1][wid] = v1; lred[2][wid] = v2; }
  __syncthreads();
  if (tid == 0) {
    float a0 = lred[0][0] + lred[0][1] + lred[0][2] + lred[0][3];
    float a1 = lred[1][0] + lred[1][1] + lred[1][2] + lred[1][3];
    float a2 = lred[2][0] + lred[2][1] + lred[2][2] + lred[2][3];
    atomicAdd(ws + DICEACC_OFF + b*3 + 0, a0);
    atomicAdd(ws + DICEACC_OFF + b*3 + 1, a1);
    atomicAdd(ws + DICEACC_OFF + b*3 + 2, a2);
  }
}

// Phase 2: pyramid max-pool at all 5 scales in one pass.
// One block per batch b; thread grid 16x16, each thread owns an 8x8 tile.
// k=2,4,8 reduce in registers; k=16 via shfl_xor {1,16}; k=32 via {2,32}.
__global__ __launch_bounds__(256) void pool_loss_kernel(float* __restrict__ ws)
{
  const int b   = blockIdx.x;
  const int tid = threadIdx.x;
  const int tr  = tid >> 4;      // 0..15 tile row
  const int tc  = tid & 15;      // 0..15 tile col
  const int r0  = tr << 3;
  const int c0  = tc << 3;

  // sum-over-projections accumulators, [vol]: 0 = P(input), 1 = G(target)
  float s2[2][4][4];
  float s4[2][2][2];
  float s8[2], s16[2], s32[2];
  #pragma unroll
  for (int v = 0; v < 2; ++v) {
    #pragma unroll
    for (int y = 0; y < 4; ++y)
      #pragma unroll
      for (int x = 0; x < 4; ++x) s2[v][y][x] = 0.f;
    #pragma unroll
    for (int y = 0; y < 2; ++y)
      #pragma unroll
      for (int x = 0; x < 2; ++x) s4[v][y][x] = 0.f;
    s8[v] = 0.f; s16[v] = 0.f; s32[v] = 0.f;
  }

  #pragma unroll
  for (int t = 0; t < 3; ++t) {
    #pragma unroll
    for (int vol = 0; vol < 2; ++vol) {
      const size_t base = ((size_t)(vol*3 + t) * B + b) * SS;
      float tile[8][8];
      if (t == 0) {
        const float* m = ws + base;
        #pragma unroll
        for (int r = 0; r < 8; ++r) {
          const float4 a = *(const float4*)(m + (size_t)(r0 + r)*S + c0);
          const float4 c = *(const float4*)(m + (size_t)(r0 + r)*S + c0 + 4);
          tile[r][0]=a.x; tile[r][1]=a.y; tile[r][2]=a.z; tile[r][3]=a.w;
          tile[r][4]=c.x; tile[r][5]=c.y; tile[r][6]=c.z; tile[r][7]=c.w;
        }
      } else {
        const uint4* m = (const uint4*)((const unsigned*)ws + base);
        #pragma unroll
        for (int r = 0; r < 8; ++r) {
          const uint4 a = m[((size_t)(r0 + r)*S + c0) >> 2];
          const uint4 c = m[((size_t)(r0 + r)*S + c0 + 4) >> 2];
          tile[r][0]=unmapf(a.x); tile[r][1]=unmapf(a.y); tile[r][2]=unmapf(a.z); tile[r][3]=unmapf(a.w);
          tile[r][4]=unmapf(c.x); tile[r][5]=unmapf(c.y); tile[r][6]=unmapf(c.z); tile[r][7]=unmapf(c.w);
        }
      }
      float m2[4][4];
      #pragma unroll
      for (int y = 0; y < 4; ++y)
        #pragma unroll
        for (int x = 0; x < 4; ++x) {
          m2[y][x] = fmaxf(fmaxf(tile[2*y][2*x], tile[2*y][2*x+1]),
                           fmaxf(tile[2*y+1][2*x], tile[2*y+1][2*x+1]));
          s2[vol][y][x] += m2[y][x];
        }
      float m4[2][2];
      #pragma unroll
      for (int y = 0; y < 2; ++y)
        #pragma unroll
        for (int x = 0; x < 2; ++x) {
          m4[y][x] = fmaxf(fmaxf(m2[2*y][2*x], m2[2*y][2*x+1]),
                           fmaxf(m2[2*y+1][2*x], m2[2*y+1][2*x+1]));
          s4[vol][y][x] += m4[y][x];
        }
      float m8 = fmaxf(fmaxf(m4[0][0], m4[0][1]), fmaxf(m4[1][0], m4[1][1]));
      s8[vol] += m8;
      float m16 = m8;
      m16 = fmaxf(m16, __shfl_xor(m16, 1, 64));
      m16 = fmaxf(m16, __shfl_xor(m16, 16, 64));
      s16[vol] += m16;
      float m32 = m16;
      m32 = fmaxf(m32, __shfl_xor(m32, 2, 64));
      m32 = fmaxf(m32, __shfl_xor(m32, 32, 64));
      s32[vol] += m32;
    }
  }

  // per-level weights: 1/(5 levels * B * n * n)
  const float w0 = 1.f/(5.f*8.f*64.f*64.f);
  const float w1 = 1.f/(5.f*8.f*32.f*32.f);
  const float w2 = 1.f/(5.f*8.f*16.f*16.f);
  const float w3 = 1.f/(5.f*8.f*8.f*8.f);
  const float w4 = 1.f/(5.f*8.f*4.f*4.f);

  float l0 = 0.f;
  #pragma unroll
  for (int y = 0; y < 4; ++y)
    #pragma unroll
    for (int x = 0; x < 4; ++x) l0 += fabsf(s2[1][y][x] - s2[0][y][x]);
  float l1 = 0.f;
  #pragma unroll
  for (int y = 0; y < 2; ++y)
    #pragma unroll
    for (int x = 0; x < 2; ++x) l1 += fabsf(s4[1][y][x] - s4[0][y][x]);
  float part = l0*w0 + l1*w1 + fabsf(s8[1] - s8[0])*w2;
  if ((tid & 0x11) == 0) part += fabsf(s16[1] - s16[0])*w3;
  if ((tid & 0x33) == 0) part += fabsf(s32[1] - s32[0])*w4;

  #pragma unroll
  for (int m = 32; m >= 1; m >>= 1) part += __shfl_xor(part, m, 64);
  __shared__ float red[4];
  const int wid = tid >> 6;
  if ((tid & 63) == 0) red[wid] = part;
  __syncthreads();
  if (tid == 0) atomicAdd(ws + LOSSACC_OFF, red[0] + red[1] + red[2] + red[3]);
}

// Phase 3: combine.
__global__ void finalize_kernel(const float* __restrict__ ws, float* __restrict__ out)
{
  if (threadIdx.x == 0) {
    float dsum = 0.f;
    for (int b = 0; b < B; ++b) {
      const float at = ws[DICEACC_OFF + b*3 + 0];
      const float aa = ws[DICEACC_OFF + b*3 + 1];
      const float tt = ws[DICEACC_OFF + b*3 + 2];
      dsum += (2.f*at + 1e-6f) / (aa + tt);
    }
    out[0] = ws[LOSSACC_OFF] + (1.f - dsum / (float)B);
  }
}

extern "C" void kernel_launch(void* const* d_in, const int* in_sizes, int n_in,
                              void* d_out, int out_size, void* d_ws, size_t ws_size,
                              hipStream_t stream)
{
  const float* gin = (const float*)d_in[0];
  const float* gtg = (const float*)d_in[1];
  float* ws  = (float*)d_ws;
  float* out = (float*)d_out;

  hipMemsetAsync(d_ws, 0, (size_t)WS_TOTAL_ELEMS * sizeof(float), stream);

  dim3 g1(4, 8, B), blk(256);
  proj_dice_kernel<<<g1, blk, 0, stream>>>(gin, gtg, ws);

  pool_loss_kernel<<<B, blk, 0, stream>>>(ws);

  finalize_kernel<<<1, 64, 0, stream>>>(ws, out);
}

// Round 3
// 78.989 us; speedup vs baseline: 5.0141x; 1.2829x over previous
//
#include <hip/hip_runtime.h>

#define S 128
#define SS (S*S)
#define B 8
#define NEG_INF (-3.402823466e+38f)

// ws layout (floats/uints):
// maps[vol(2)][t(3)][b(8)][SS] : t=0 Pa(float, [i][j]), t=1 Pb(mapped uint, [j][k]), t=2 Pc(mapped uint, [i][k])
#define MAPS_ELEMS (2*3*B*SS)        // 786432
#define LOSSACC_OFF MAPS_ELEMS       // 1 float topo accumulator (+7 pad)
#define DICEACC_OFF (MAPS_ELEMS + 8) // 24 floats: [b][{at,aa,tt}]
#define WS_TOTAL_ELEMS (MAPS_ELEMS + 8 + 24)

__device__ __forceinline__ unsigned mapf(float f) {
  unsigned u = __float_as_uint(f);
  return (u & 0x80000000u) ? ~u : (u | 0x80000000u);
}
__device__ __forceinline__ float unmapf(unsigned u) {
  return (u & 0x80000000u) ? __uint_as_float(u & 0x7FFFFFFFu) : __uint_as_float(~u);
}
__device__ __forceinline__ float4 max4(float4 a, float4 b) {
  return make_float4(fmaxf(a.x,b.x), fmaxf(a.y,b.y), fmaxf(a.z,b.z), fmaxf(a.w,b.w));
}
__device__ __forceinline__ float hmax4(float4 a) {
  return fmaxf(fmaxf(a.x,a.y), fmaxf(a.z,a.w));
}
__device__ __forceinline__ float4 shflx4(float4 v, int m) {
  return make_float4(__shfl_xor(v.x,m,64), __shfl_xor(v.y,m,64),
                     __shfl_xor(v.z,m,64), __shfl_xor(v.w,m,64));
}

// Phase 1: stream channel-1 of both volumes once; projections + dice sums.
// Block = 16 i x 32 j x 128 k, 1024 threads: thread = (jr = tid>>5, kl = tid&31),
// iterates 16 i's with one float4 per tensor per i.
__global__ __launch_bounds__(1024, 4) void proj_dice_kernel(
    const float* __restrict__ gin, const float* __restrict__ gtg,
    float* __restrict__ ws)
{
  const int jc  = blockIdx.x;   // 0..3  -> j chunk of 32
  const int ic  = blockIdx.y;   // 0..7  -> i chunk of 16
  const int b   = blockIdx.z;   // 0..7
  const int tid = threadIdx.x;
  const int jr  = tid >> 5;     // 0..31
  const int kl  = tid & 31;     // 0..31
  const int j   = (jc << 5) + jr;
  const int i0  = ic << 4;
  const int k0  = kl << 2;
  const int w   = tid >> 6;     // wave 0..15
  const int l   = tid & 63;

  const float* __restrict__ xin = gin + (size_t)(2*b + 1) * (size_t)(S*SS);
  const float* __restrict__ xtg = gtg + (size_t)(2*b + 1) * (size_t)(S*SS);

  float*    paI = ws + (size_t)(0*B + b) * SS;
  float*    paT = ws + (size_t)(3*B + b) * SS;
  unsigned* pbI = (unsigned*)ws + (size_t)(1*B + b) * SS;
  unsigned* pbT = (unsigned*)ws + (size_t)(4*B + b) * SS;
  unsigned* pcI = (unsigned*)ws + (size_t)(2*B + b) * SS;
  unsigned* pcT = (unsigned*)ws + (size_t)(5*B + b) * SS;

  // parity-double-buffered per-wave Pc partials: [parity][tensor][wave][k]
  __shared__ float lpc[2][2][16][S];   // 32 KB
  __shared__ float dred[16][3];

  float4 pba = make_float4(NEG_INF, NEG_INF, NEG_INF, NEG_INF);
  float4 pbt = pba;
  float s_at = 0.f, s_aa = 0.f, s_tt = 0.f;

  #pragma unroll 2
  for (int ii = 0; ii < 16; ++ii) {
    const int i = i0 + ii;
    const size_t off = (size_t)i*SS + (size_t)j*S + k0;
    const float4 a = *(const float4*)(xin + off);
    const float4 t = *(const float4*)(xtg + off);

    s_at = fmaf(a.x,t.x, fmaf(a.y,t.y, fmaf(a.z,t.z, fmaf(a.w,t.w, s_at))));
    s_aa = fmaf(a.x,a.x, fmaf(a.y,a.y, fmaf(a.z,a.z, fmaf(a.w,a.w, s_aa))));
    s_tt = fmaf(t.x,t.x, fmaf(t.y,t.y, fmaf(t.z,t.z, fmaf(t.w,t.w, s_tt))));

    // Pa[i][j]: row max over k (32 lanes of same jr = one 32-half of the wave)
    float rma = hmax4(a), rmt = hmax4(t);
    #pragma unroll
    for (int m = 16; m >= 1; m >>= 1) {
      rma = fmaxf(rma, __shfl_xor(rma, m, 64));
      rmt = fmaxf(rmt, __shfl_xor(rmt, m, 64));
    }
    if (kl == 0) { paI[i*S + j] = rma; paT[i*S + j] = rmt; }

    // Pb accumulate over i
    pba = max4(pba, a);
    pbt = max4(pbt, t);

    // Pc: combine jr-pair within wave, then cross-wave via LDS
    const float4 pca = max4(a, shflx4(a, 32));
    const float4 pct = max4(t, shflx4(t, 32));
    const int par = ii & 1;
    if (l < 32) {
      *(float4*)&lpc[par][0][w][k0] = pca;
      *(float4*)&lpc[par][1][w][k0] = pct;
    }
    __syncthreads();
    if (tid < 256) {
      const int tensor = tid >> 7;
      const int k = tid & 127;
      float m = lpc[par][tensor][0][k];
      #pragma unroll
      for (int r = 1; r < 16; ++r) m = fmaxf(m, lpc[par][tensor][r][k]);
      atomicMax((tensor ? pcT : pcI) + i*S + k, mapf(m));
    }
  }

  // flush Pb[j][k] (max over this block's 16 i's)
  atomicMax(pbI + j*S + k0+0, mapf(pba.x));
  atomicMax(pbI + j*S + k0+1, mapf(pba.y));
  atomicMax(pbI + j*S + k0+2, mapf(pba.z));
  atomicMax(pbI + j*S + k0+3, mapf(pba.w));
  atomicMax(pbT + j*S + k0+0, mapf(pbt.x));
  atomicMax(pbT + j*S + k0+1, mapf(pbt.y));
  atomicMax(pbT + j*S + k0+2, mapf(pbt.z));
  atomicMax(pbT + j*S + k0+3, mapf(pbt.w));

  // dice reduction
  float v0 = s_at, v1 = s_aa, v2 = s_tt;
  #pragma unroll
  for (int m = 32; m >= 1; m >>= 1) {
    v0 += __shfl_xor(v0, m, 64);
    v1 += __shfl_xor(v1, m, 64);
    v2 += __shfl_xor(v2, m, 64);
  }
  if (l == 0) { dred[w][0] = v0; dred[w][1] = v1; dred[w][2] = v2; }
  __syncthreads();
  if (tid == 0) {
    float a0 = 0.f, a1 = 0.f, a2 = 0.f;
    #pragma unroll
    for (int r = 0; r < 16; ++r) { a0 += dred[r][0]; a1 += dred[r][1]; a2 += dred[r][2]; }
    atomicAdd(ws + DICEACC_OFF + b*3 + 0, a0);
    atomicAdd(ws + DICEACC_OFF + b*3 + 1, a1);
    atomicAdd(ws + DICEACC_OFF + b*3 + 2, a2);
  }
}

// Phase 2: pyramid max-pool at all 5 scales in one pass.
// One block per batch b; thread grid 16x16, each thread owns an 8x8 tile.
// k=2,4,8 reduce in registers; k=16 via shfl_xor {1,16}; k=32 via {2,32}.
__global__ __launch_bounds__(256) void pool_loss_kernel(float* __restrict__ ws)
{
  const int b   = blockIdx.x;
  const int tid = threadIdx.x;
  const int tr  = tid >> 4;      // 0..15 tile row
  const int tc  = tid & 15;      // 0..15 tile col
  const int r0  = tr << 3;
  const int c0  = tc << 3;

  // sum-over-projections accumulators, [vol]: 0 = P(input), 1 = G(target)
  float s2[2][4][4];
  float s4[2][2][2];
  float s8[2], s16[2], s32[2];
  #pragma unroll
  for (int v = 0; v < 2; ++v) {
    #pragma unroll
    for (int y = 0; y < 4; ++y)
      #pragma unroll
      for (int x = 0; x < 4; ++x) s2[v][y][x] = 0.f;
    #pragma unroll
    for (int y = 0; y < 2; ++y)
      #pragma unroll
      for (int x = 0; x < 2; ++x) s4[v][y][x] = 0.f;
    s8[v] = 0.f; s16[v] = 0.f; s32[v] = 0.f;
  }

  #pragma unroll
  for (int t = 0; t < 3; ++t) {
    #pragma unroll
    for (int vol = 0; vol < 2; ++vol) {
      const size_t base = ((size_t)(vol*3 + t) * B + b) * SS;
      float tile[8][8];
      if (t == 0) {
        const float* m = ws + base;
        #pragma unroll
        for (int r = 0; r < 8; ++r) {
          const float4 a = *(const float4*)(m + (size_t)(r0 + r)*S + c0);
          const float4 c = *(const float4*)(m + (size_t)(r0 + r)*S + c0 + 4);
          tile[r][0]=a.x; tile[r][1]=a.y; tile[r][2]=a.z; tile[r][3]=a.w;
          tile[r][4]=c.x; tile[r][5]=c.y; tile[r][6]=c.z; tile[r][7]=c.w;
        }
      } else {
        const uint4* m = (const uint4*)((const unsigned*)ws + base);
        #pragma unroll
        for (int r = 0; r < 8; ++r) {
          const uint4 a = m[((size_t)(r0 + r)*S + c0) >> 2];
          const uint4 c = m[((size_t)(r0 + r)*S + c0 + 4) >> 2];
          tile[r][0]=unmapf(a.x); tile[r][1]=unmapf(a.y); tile[r][2]=unmapf(a.z); tile[r][3]=unmapf(a.w);
          tile[r][4]=unmapf(c.x); tile[r][5]=unmapf(c.y); tile[r][6]=unmapf(c.z); tile[r][7]=unmapf(c.w);
        }
      }
      float m2[4][4];
      #pragma unroll
      for (int y = 0; y < 4; ++y)
        #pragma unroll
        for (int x = 0; x < 4; ++x) {
          m2[y][x] = fmaxf(fmaxf(tile[2*y][2*x], tile[2*y][2*x+1]),
                           fmaxf(tile[2*y+1][2*x], tile[2*y+1][2*x+1]));
          s2[vol][y][x] += m2[y][x];
        }
      float m4[2][2];
      #pragma unroll
      for (int y = 0; y < 2; ++y)
        #pragma unroll
        for (int x = 0; x < 2; ++x) {
          m4[y][x] = fmaxf(fmaxf(m2[2*y][2*x], m2[2*y][2*x+1]),
                           fmaxf(m2[2*y+1][2*x], m2[2*y+1][2*x+1]));
          s4[vol][y][x] += m4[y][x];
        }
      float m8 = fmaxf(fmaxf(m4[0][0], m4[0][1]), fmaxf(m4[1][0], m4[1][1]));
      s8[vol] += m8;
      float m16 = m8;
      m16 = fmaxf(m16, __shfl_xor(m16, 1, 64));
      m16 = fmaxf(m16, __shfl_xor(m16, 16, 64));
      s16[vol] += m16;
      float m32 = m16;
      m32 = fmaxf(m32, __shfl_xor(m32, 2, 64));
      m32 = fmaxf(m32, __shfl_xor(m32, 32, 64));
      s32[vol] += m32;
    }
  }

  // per-level weights: 1/(5 levels * B * n * n)
  const float w0 = 1.f/(5.f*8.f*64.f*64.f);
  const float w1 = 1.f/(5.f*8.f*32.f*32.f);
  const float w2 = 1.f/(5.f*8.f*16.f*16.f);
  const float w3 = 1.f/(5.f*8.f*8.f*8.f);
  const float w4 = 1.f/(5.f*8.f*4.f*4.f);

  float l0 = 0.f;
  #pragma unroll
  for (int y = 0; y < 4; ++y)
    #pragma unroll
    for (int x = 0; x < 4; ++x) l0 += fabsf(s2[1][y][x] - s2[0][y][x]);
  float l1 = 0.f;
  #pragma unroll
  for (int y = 0; y < 2; ++y)
    #pragma unroll
    for (int x = 0; x < 2; ++x) l1 += fabsf(s4[1][y][x] - s4[0][y][x]);
  float part = l0*w0 + l1*w1 + fabsf(s8[1] - s8[0])*w2;
  if ((tid & 0x11) == 0) part += fabsf(s16[1] - s16[0])*w3;
  if ((tid & 0x33) == 0) part += fabsf(s32[1] - s32[0])*w4;

  #pragma unroll
  for (int m = 32; m >= 1; m >>= 1) part += __shfl_xor(part, m, 64);
  __shared__ float red[4];
  const int wid = tid >> 6;
  if ((tid & 63) == 0) red[wid] = part;
  __syncthreads();
  if (tid == 0) atomicAdd(ws + LOSSACC_OFF, red[0] + red[1] + red[2] + red[3]);
}

// Phase 3: combine.
__global__ void finalize_kernel(const float* __restrict__ ws, float* __restrict__ out)
{
  if (threadIdx.x == 0) {
    float dsum = 0.f;
    for (int b = 0; b < B; ++b) {
      const float at = ws[DICEACC_OFF + b*3 + 0];
      const float aa = ws[DICEACC_OFF + b*3 + 1];
      const float tt = ws[DICEACC_OFF + b*3 + 2];
      dsum += (2.f*at + 1e-6f) / (aa + tt);
    }
    out[0] = ws[LOSSACC_OFF] + (1.f - dsum / (float)B);
  }
}

extern "C" void kernel_launch(void* const* d_in, const int* in_sizes, int n_in,
                              void* d_out, int out_size, void* d_ws, size_t ws_size,
                              hipStream_t stream)
{
  const float* gin = (const float*)d_in[0];
  const float* gtg = (const float*)d_in[1];
  float* ws  = (float*)d_ws;
  float* out = (float*)d_out;

  hipMemsetAsync(d_ws, 0, (size_t)WS_TOTAL_ELEMS * sizeof(float), stream);

  dim3 g1(4, 8, B);
  proj_dice_kernel<<<g1, dim3(1024), 0, stream>>>(gin, gtg, ws);

  pool_loss_kernel<<<B, dim3(256), 0, stream>>>(ws);

  finalize_kernel<<<1, 64, 0, stream>>>(ws, out);
}